// Round 8
// baseline (323.524 us; speedup 1.0000x reference)
//
#include <hip/hip_runtime.h>

typedef _Float16 f16;
typedef _Float16 f16x2 __attribute__((ext_vector_type(2)));
typedef _Float16 f16x4 __attribute__((ext_vector_type(4)));
typedef _Float16 f16x8 __attribute__((ext_vector_type(8)));
typedef float f32x4 __attribute__((ext_vector_type(4)));
typedef unsigned int uint;

#define KM 0.1f   // DT * TAU_MEM_INV
#define KS 0.8f   // 1 - DT * TAU_SYN_INV
#define AS1 __attribute__((address_space(1)))
#define AS3 __attribute__((address_space(3)))
#define EPS_LO 2.44140625e-4f  // 2^-12

// ---------- E1: enc+LIF0 sim -> spike bitmask Z[b][f] + column flags ----------
__global__ void enc_flags(const float* __restrict__ img, uint* __restrict__ Z,
                          uint* __restrict__ flags) {
  int idx = blockIdx.x * 256 + threadIdx.x;
  if (idx >= 128 * 6000) return;
  int b = idx / 6000, f = (idx - b * 6000) << 1;
  float2 t2 = *(const float2*)&img[b * 12000 + f];
  float x0 = t2.x, x1 = t2.y;
  float ve0 = 0.f, vl0 = 0.f, il0 = 0.f;
  float ve1 = 0.f, vl1 = 0.f, il1 = 0.f;
  uint m0 = 0u, m1 = 0u;
  for (int t = 0; t < 32; ++t) {
    ve0 = ve0 + KM * (x0 - ve0);
    ve1 = ve1 + KM * (x1 - ve1);
    float z0a = (ve0 > 1.0f) ? 1.f : 0.f;
    float z0b = (ve1 > 1.0f) ? 1.f : 0.f;
    ve0 -= z0a * ve0; ve1 -= z0b * ve1;
    float vd0 = vl0 + KM * (il0 - vl0), id0 = KS * il0;
    float vd1 = vl1 + KM * (il1 - vl1), id1 = KS * il1;
    float z1a = (vd0 > 1.0f) ? 1.f : 0.f;
    float z1b = (vd1 > 1.0f) ? 1.f : 0.f;
    m0 |= (vd0 > 1.0f) ? (1u << t) : 0u;
    m1 |= (vd1 > 1.0f) ? (1u << t) : 0u;
    vl0 = (1.f - z1a) * vd0; il0 = id0 + z0a;
    vl1 = (1.f - z1b) * vd1; il1 = id1 + z0b;
  }
  Z[b * 12032 + f] = m0;
  Z[b * 12032 + f + 1] = m1;
  uint mask = (m0 ? 1u : 0u) << (f & 31) | (m1 ? 1u : 0u) << ((f & 31) + 1);
  if (mask) atomicOr(&flags[f >> 5], mask);
}

// ---------- E2: popcount scan -> sorted colidx, inverse map pos[f], meta={K', Kpc} ----------
__global__ void scan_cols(const uint* __restrict__ flags, int* __restrict__ colidx,
                          int* __restrict__ pos, int* __restrict__ meta) {
  __shared__ int cnt[512];
  int t = threadIdx.x;
  uint w = (t < 376) ? flags[t] : 0u;
  cnt[t] = __popc(w);
  __syncthreads();
  for (int off = 1; off < 512; off <<= 1) {
    int v = cnt[t];
    int u = (t >= off) ? cnt[t - off] : 0;
    __syncthreads();
    cnt[t] = v + u;
    __syncthreads();
  }
  int base = cnt[t] - __popc(w);  // exclusive prefix
  int rank = 0;
  for (int bit = 0; bit < 32; ++bit) {
    int f = t * 32 + bit;
    if (f < 12032) {
      int alive = (int)((w >> bit) & 1u);
      if (alive) colidx[base + rank] = f;
      pos[f] = alive ? (base + rank) : -1;
      rank += alive;
    }
  }
  if (t == 511) {
    int K = cnt[511];
    meta[0] = K;
    meta[1] = (K + 63) & ~63;
  }
}

// ---------- E3: compacted A'[4096][Kpc] from Z bitmasks (no FP, exact) ----------
__global__ void spike_gather(const uint* __restrict__ Z, f16* __restrict__ A,
                             const int* __restrict__ colidx, const int* __restrict__ meta) {
  int K = meta[0], Kpc = meta[1];
  if (Kpc == 0) return;
  int jp = Kpc >> 1;
  int total = 128 * jp;
  for (int i = blockIdx.x * 256 + threadIdx.x; i < total; i += gridDim.x * 256) {
    int b = i / jp, j = (i - b * jp) << 1;
    uint m0 = (j < K) ? Z[b * 12032 + colidx[j]] : 0u;
    uint m1 = (j + 1 < K) ? Z[b * 12032 + colidx[j + 1]] : 0u;
    size_t base = (size_t)b * Kpc + j;
    size_t stride = (size_t)128 * Kpc;
    for (int t = 0; t < 32; ++t) {
      f16x2 s;
      s[0] = (f16)(float)((m0 >> t) & 1u);
      s[1] = (f16)(float)((m1 >> t) & 1u);
      *(f16x2*)&A[base + (size_t)t * stride] = s;
    }
  }
}

// ---------- P0: coalesced-read scatter-write layer-0 weight prep (interleaved hi/lo) ----------
__global__ void prep_w0_scatter(const float* __restrict__ W, f16* __restrict__ dst,
                                const int* __restrict__ pos, const int* __restrict__ meta) {
  int Kpc = meta[1];
  if (Kpc == 0) return;
  int total = 2048 * 3000;  // rows (padded to 2048) x 12000/4
  for (int i = blockIdx.x * 256 + threadIdx.x; i < total; i += gridDim.x * 256) {
    int o = i / 3000;
    int f4 = (i - o * 3000) << 2;
    float w[4] = {0.f, 0.f, 0.f, 0.f};
    if (o < 2000) {
      float4 t = *(const float4*)&W[(size_t)o * 12000 + f4];
      w[0] = t.x; w[1] = t.y; w[2] = t.z; w[3] = t.w;
    }
    int r2 = ((o >> 4) << 5) + (o & 15);  // hi row; +16 = lo row
    size_t rh = (size_t)r2 * Kpc;
    size_t rl = (size_t)(r2 + 16) * Kpc;
#pragma unroll
    for (int e = 0; e < 4; ++e) {
      int p = pos[f4 + e];
      if (p >= 0) {
        f16 h = (f16)w[e];
        float hf = (float)h;
        if (__builtin_fabsf(hf) < 6.103515625e-05f) { h = (f16)0.f; hf = 0.f; }
        f16 l = (f16)((w[e] - hf) * 4096.0f);
        dst[rh + p] = h;
        dst[rl + p] = l;
      }
    }
  }
}

// ---------- zero the [K,Kpc) column pad of the layer-0 W2 ----------
__global__ void zero_tail(f16* __restrict__ dst, const int* __restrict__ meta) {
  int K = meta[0], Kpc = meta[1];
  int i = blockIdx.x * 256 + threadIdx.x;  // 4096*64 threads
  int r2 = i >> 6, j = K + (i & 63);
  if (j < Kpc) dst[(size_t)r2 * Kpc + j] = (f16)0.f;
}

// ---------- weight prep for layers 1..5 (all interleaved W2) ----------
struct PrepArgs {
  const float* W[5];
  f16* dst[5];
  int Nr[5], Kr[5], Kp[5], Npd[5];
  int boff[6];
};

__global__ void prep_w_all(PrepArgs a) {
  int blk = blockIdx.x;
  int k = 0;
#pragma unroll
  for (int j = 0; j < 4; ++j) k += (blk >= a.boff[j + 1]) ? 1 : 0;
  int i = (blk - a.boff[k]) * 256 + threadIdx.x;
  int Kp = a.Kp[k];
  int kp4 = Kp >> 2;
  int total4 = a.Npd[k] * kp4;
  if (i >= total4) return;
  int o = i / kp4, f = (i - o * kp4) << 2;
  float w[4] = {0.f, 0.f, 0.f, 0.f};
  if (o < a.Nr[k] && f < a.Kr[k]) {
    float4 t = *(const float4*)&a.W[k][(size_t)o * a.Kr[k] + f];
    w[0] = t.x; w[1] = t.y; w[2] = t.z; w[3] = t.w;
  }
  f16x4 h4, l4;
#pragma unroll
  for (int e = 0; e < 4; ++e) {
    f16 h = (f16)w[e];
    float hf = (float)h;
    if (__builtin_fabsf(hf) < 6.103515625e-05f) { h = (f16)0.f; hf = 0.f; }
    h4[e] = h;
    l4[e] = (f16)((w[e] - hf) * 4096.0f);
  }
  int r2 = ((o >> 4) << 5) + (o & 15);
  *(f16x4*)&a.dst[k][(size_t)r2 * Kp + f] = h4;
  *(f16x4*)&a.dst[k][(size_t)(r2 + 16) * Kp + f] = l4;
}

// ---------- big-tile GEMM (all layers): BM=256, BN=128 W2-rows, 8 waves ----------
// K from device memory when kpcp != nullptr (layer 0 compacted K).
__launch_bounds__(512, 4)
__global__ void gemm_big(const f16* __restrict__ A, const f16* __restrict__ B2,
                         float* __restrict__ C, const int* __restrict__ kpcp,
                         int KpFixed, int Np) {
  __shared__ f16 sA[256 * 64];  // 32 KiB
  __shared__ f16 sB[128 * 64];  // 16 KiB
  const int Kp = kpcp ? kpcp[1] : KpFixed;
  const int tid = threadIdx.x;
  const int lane = tid & 63;
  const int wave = tid >> 6;
  const int wr = wave >> 1;
  const int wc = wave & 1;

  const int nx = gridDim.x;
  const int flat = blockIdx.y * nx + blockIdx.x;
  const int cpx = (nx * gridDim.y) >> 3;
  const int id = (flat & 7) * cpx + (flat >> 3);
  const int m0 = (id / nx) * 256;
  const int n0 = (id % nx) * 128;

  f32x4 zero = {0.f, 0.f, 0.f, 0.f};
  f32x4 acc[4][4];
#pragma unroll
  for (int m = 0; m < 4; ++m)
#pragma unroll
    for (int n = 0; n < 4; ++n) acc[m][n] = zero;

  const f16* Abase = A + (size_t)m0 * Kp;
  const f16* Bbase = B2 + (size_t)n0 * Kp;
  const int nkt = Kp >> 6;
  for (int kt = 0; kt < nkt; ++kt) {
    __syncthreads();
    const f16* Ab = Abase + (size_t)kt * 64;
    const f16* Bb = Bbase + (size_t)kt * 64;
#pragma unroll
    for (int j = 0; j < 4; ++j) {
      int q = j * 512 + tid;
      int r = q >> 3, c = ((q & 7) ^ (r & 7)) * 8;
      __builtin_amdgcn_global_load_lds((const AS1 void*)(Ab + (size_t)r * Kp + c),
                                       (AS3 void*)(&sA[q * 8]), 16, 0, 0);
    }
#pragma unroll
    for (int j = 0; j < 2; ++j) {
      int q = j * 512 + tid;
      int r = q >> 3, c = ((q & 7) ^ (r & 7)) * 8;
      __builtin_amdgcn_global_load_lds((const AS1 void*)(Bb + (size_t)r * Kp + c),
                                       (AS3 void*)(&sB[q * 8]), 16, 0, 0);
    }
    __syncthreads();
#pragma unroll
    for (int kk = 0; kk < 2; ++kk) {
      const int lr = lane & 15;
      const int hq = lane >> 4;
      f16x8 af[4], bf[4];
#pragma unroll
      for (int m = 0; m < 4; ++m) {
        int R = wr * 64 + m * 16 + lr;
        int ch = (kk * 4 + hq) ^ (R & 7);
        af[m] = *(const f16x8*)&sA[R * 64 + ch * 8];
      }
#pragma unroll
      for (int n = 0; n < 4; ++n) {
        int R = wc * 64 + n * 16 + lr;
        int ch = (kk * 4 + hq) ^ (R & 7);
        bf[n] = *(const f16x8*)&sB[R * 64 + ch * 8];
      }
#pragma unroll
      for (int m = 0; m < 4; ++m)
#pragma unroll
        for (int n = 0; n < 4; ++n)
          acc[m][n] = __builtin_amdgcn_mfma_f32_16x16x32_f16(af[m], bf[n], acc[m][n], 0, 0, 0);
    }
  }

  const int lr = lane & 15, lq = lane >> 4;
#pragma unroll
  for (int m = 0; m < 4; ++m)
#pragma unroll
    for (int j = 0; j < 2; ++j) {
      int col = (n0 >> 1) + wc * 32 + j * 16 + lr;
#pragma unroll
      for (int i = 0; i < 4; ++i) {
        int row = m0 + wr * 64 + m * 16 + lq * 4 + i;
        C[(size_t)row * Np + col] = acc[m][2 * j][i] + EPS_LO * acc[m][2 * j + 1][i];
      }
    }
}

// ---------- LI_k + LIF_{k+1}, 4 neurons per thread ----------
__global__ void li_lif(const float* __restrict__ G, f16* __restrict__ Sn, int Np) {
  int np4 = Np >> 2;
  int idx = blockIdx.x * 256 + threadIdx.x;
  if (idx >= 128 * np4) return;
  int b = idx / np4, n = (idx - b * np4) << 2;
  size_t base = (size_t)b * Np + n;
  size_t stride = (size_t)128 * Np;
  float vL[4] = {0.f, 0.f, 0.f, 0.f}, iL[4] = {0.f, 0.f, 0.f, 0.f};
  float vF[4] = {0.f, 0.f, 0.f, 0.f}, iF[4] = {0.f, 0.f, 0.f, 0.f};
  for (int t = 0; t < 32; ++t) {
    float4 g4 = *(const float4*)&G[base + t * stride];
    float g[4] = {g4.x, g4.y, g4.z, g4.w};
    f16x4 s;
#pragma unroll
    for (int e = 0; e < 4; ++e) {
      float ij = iL[e] + g[e];
      vL[e] = vL[e] + KM * (ij - vL[e]);
      iL[e] = KS * ij;
      float vd = vF[e] + KM * (iF[e] - vF[e]);
      float id = KS * iF[e];
      float z = (vd > 1.0f) ? 1.f : 0.f;
      vF[e] = (1.f - z) * vd;
      iF[e] = id + vL[e];
      s[e] = (f16)z;
    }
    *(f16x4*)&Sn[base + t * stride] = s;
  }
}

// ---------- LI5 scan + max over t + log_softmax ----------
__global__ void final_k(const float* __restrict__ G, float* __restrict__ out) {
  int b = blockIdx.x;
  int n = threadIdx.x;
  float vL = 0.f, iL = 0.f, mx = -3.4e38f;
  for (int t = 0; t < 32; ++t) {
    float g = G[(size_t)(t * 128 + b) * 128 + n];
    float ij = iL + g;
    vL = vL + KM * (ij - vL);
    iL = KS * ij;
    mx = fmaxf(mx, vL);
  }
  float v = (n < 10) ? mx : -3.4e38f;
  float M = v;
#pragma unroll
  for (int s = 1; s < 16; s <<= 1) M = fmaxf(M, __shfl_xor(M, s));
  float e = (n < 10) ? expf(v - M) : 0.f;
  float sum = e;
#pragma unroll
  for (int s = 1; s < 16; s <<= 1) sum += __shfl_xor(sum, s);
  if (n < 10) out[b * 10 + n] = v - M - logf(sum);
}

extern "C" void kernel_launch(void* const* d_in, const int* in_sizes, int n_in,
                              void* d_out, int out_size, void* d_ws, size_t ws_size,
                              hipStream_t stream) {
  const float* img = (const float*)d_in[0];
  static const int Nr[6]  = {2000, 1500, 1000, 500, 100, 10};
  static const int Kr[6]  = {12000, 2000, 1500, 1000, 500, 100};
  static const int Npd[6] = {2048, 1536, 1024, 512, 128, 128};
  static const int Kpd[6] = {12032, 2048, 1536, 1024, 512, 128};

  char* p = (char*)d_ws;
  f16* wa[6];  // interleaved W2 [2*Npd][Kp] for all layers (layer 0 compacted K)
  wa[0] = (f16*)p; p += (size_t)4096 * 12032 * 2;  // max compacted size
  for (int k = 1; k < 6; ++k) {
    wa[k] = (f16*)p; p += (size_t)2 * Npd[k] * Kpd[k] * 2;
  }
  f16* S = (f16*)p;  p += (size_t)4096 * 12032 * 2;  // compact A (L0) / spike buffers
  float* G = (float*)p; p += (size_t)4096 * 2048 * 4;
  uint* Z = (uint*)p; p += (size_t)128 * 12032 * 4;  // spike bitmasks
  uint* flags = (uint*)p; p += 376 * 4;
  int* colidx = (int*)p; p += 12032 * 4;
  int* pos = (int*)p; p += 12032 * 4;
  int* meta = (int*)p; p += 2 * 4;

  // --- layer-0 column compaction chain ---
  hipMemsetAsync(flags, 0, 376 * 4, stream);
  enc_flags<<<(128 * 6000 + 255) / 256, 256, 0, stream>>>(img, Z, flags);
  scan_cols<<<1, 512, 0, stream>>>(flags, colidx, pos, meta);
  spike_gather<<<1024, 256, 0, stream>>>(Z, S, colidx, meta);
  prep_w0_scatter<<<8192, 256, 0, stream>>>((const float*)d_in[1], wa[0], pos, meta);
  zero_tail<<<(4096 * 64) / 256, 256, 0, stream>>>(wa[0], meta);

  // --- layers 1..5 weight prep (all interleaved) ---
  PrepArgs pa;
  int nb = 0;
  for (int k = 1; k < 6; ++k) {
    int kk = k - 1;
    pa.W[kk] = (const float*)d_in[k + 1];
    pa.dst[kk] = wa[k];
    pa.Nr[kk] = Nr[k]; pa.Kr[kk] = Kr[k]; pa.Kp[kk] = Kpd[k]; pa.Npd[kk] = Npd[k];
    pa.boff[kk] = nb;
    nb += ((Npd[k] * Kpd[k]) >> 2) / 256;
  }
  pa.boff[5] = nb;
  prep_w_all<<<nb, 256, 0, stream>>>(pa);

  // --- layer pipeline: all GEMMs via gemm_big ---
  for (int k = 0; k < 6; ++k) {
    if (k == 0) {
      gemm_big<<<dim3(2 * Npd[0] / 128, 16), dim3(512), 0, stream>>>(
          S, wa[0], G, meta, 0, Npd[0]);
    } else {
      gemm_big<<<dim3(2 * Npd[k] / 128, 16), dim3(512), 0, stream>>>(
          S, wa[k], G, nullptr, Kpd[k], Npd[k]);
    }
    if (k < 5)
      li_lif<<<(128 * (Npd[k] >> 2) + 255) / 256, 256, 0, stream>>>(G, S, Npd[k]);
  }
  final_k<<<128, 64, 0, stream>>>(G, (float*)d_out);
}

// Round 9
// 307.969 us; speedup vs baseline: 1.0505x; 1.0505x over previous
//
#include <hip/hip_runtime.h>

typedef _Float16 f16;
typedef _Float16 f16x2 __attribute__((ext_vector_type(2)));
typedef _Float16 f16x4 __attribute__((ext_vector_type(4)));
typedef _Float16 f16x8 __attribute__((ext_vector_type(8)));
typedef float f32x4 __attribute__((ext_vector_type(4)));
typedef unsigned int uint;

#define KM 0.1f   // DT * TAU_MEM_INV
#define KS 0.8f   // 1 - DT * TAU_SYN_INV
#define AS1 __attribute__((address_space(1)))
#define AS3 __attribute__((address_space(3)))
#define EPS_LO 2.44140625e-4f  // 2^-12

// ---------- E1: enc+LIF0 sim (float4) -> spike bitmask Z[b][f] + column flags ----------
__global__ void enc_flags(const float* __restrict__ img, uint* __restrict__ Z,
                          uint* __restrict__ flags) {
  int idx = blockIdx.x * 256 + threadIdx.x;
  if (idx >= 128 * 3000) return;
  int b = idx / 3000, f = (idx - b * 3000) << 2;
  float4 t4 = *(const float4*)&img[b * 12000 + f];
  float x[4] = {t4.x, t4.y, t4.z, t4.w};
  float ve[4] = {0.f, 0.f, 0.f, 0.f}, vl[4] = {0.f, 0.f, 0.f, 0.f}, il[4] = {0.f, 0.f, 0.f, 0.f};
  uint m[4] = {0u, 0u, 0u, 0u};
  for (int t = 0; t < 32; ++t) {
#pragma unroll
    for (int e = 0; e < 4; ++e) {
      ve[e] = ve[e] + KM * (x[e] - ve[e]);
      float z0 = (ve[e] > 1.0f) ? 1.f : 0.f;
      ve[e] -= z0 * ve[e];
      float vd = vl[e] + KM * (il[e] - vl[e]);
      float id = KS * il[e];
      float z1 = (vd > 1.0f) ? 1.f : 0.f;
      m[e] |= (vd > 1.0f) ? (1u << t) : 0u;
      vl[e] = (1.f - z1) * vd;
      il[e] = id + z0;
    }
  }
  *(uint4*)&Z[b * 12032 + f] = make_uint4(m[0], m[1], m[2], m[3]);
  uint mask = 0u;
#pragma unroll
  for (int e = 0; e < 4; ++e) mask |= (m[e] ? 1u : 0u) << ((f & 31) + e);
  // 8-lane (one flag word) shuffle-OR pre-reduce, then one atomic per group
  int lane = threadIdx.x & 63;
#pragma unroll
  for (int s = 1; s < 8; s <<= 1) mask |= (uint)__shfl_xor((int)mask, s);
  if ((lane & 7) == 0 && mask) atomicOr(&flags[f >> 5], mask);
}

// ---------- E2: popcount scan -> sorted colidx, inverse map pos[f], meta={K', Kpc} ----------
__global__ void scan_cols(const uint* __restrict__ flags, int* __restrict__ colidx,
                          int* __restrict__ pos, int* __restrict__ meta) {
  __shared__ int cnt[512];
  int t = threadIdx.x;
  uint w = (t < 376) ? flags[t] : 0u;
  cnt[t] = __popc(w);
  __syncthreads();
  for (int off = 1; off < 512; off <<= 1) {
    int v = cnt[t];
    int u = (t >= off) ? cnt[t - off] : 0;
    __syncthreads();
    cnt[t] = v + u;
    __syncthreads();
  }
  int base = cnt[t] - __popc(w);  // exclusive prefix
  int rank = 0;
  for (int bit = 0; bit < 32; ++bit) {
    int f = t * 32 + bit;
    if (f < 12032) {
      int alive = (int)((w >> bit) & 1u);
      if (alive) colidx[base + rank] = f;
      pos[f] = alive ? (base + rank) : -1;
      rank += alive;
    }
  }
  if (t == 511) {
    int K = cnt[511];
    meta[0] = K;
    meta[1] = (K + 63) & ~63;
  }
}

// ---------- E3: compacted A'[4096][Kpc] from Z bitmasks; row = b*32 + t ----------
__global__ void spike_gather(const uint* __restrict__ Z, f16* __restrict__ A,
                             const int* __restrict__ colidx, const int* __restrict__ meta) {
  int K = meta[0], Kpc = meta[1];
  if (Kpc == 0) return;
  int jp = Kpc >> 1;
  int total = 128 * jp;
  for (int i = blockIdx.x * 256 + threadIdx.x; i < total; i += gridDim.x * 256) {
    int b = i / jp, j = (i - b * jp) << 1;
    uint m0 = (j < K) ? Z[b * 12032 + colidx[j]] : 0u;
    uint m1 = (j + 1 < K) ? Z[b * 12032 + colidx[j + 1]] : 0u;
    size_t rowbase = (size_t)b * 32 * Kpc + j;
    for (int t = 0; t < 32; ++t) {
      f16x2 s;
      s[0] = (f16)(float)((m0 >> t) & 1u);
      s[1] = (f16)(float)((m1 >> t) & 1u);
      *(f16x2*)&A[rowbase + (size_t)t * Kpc] = s;
    }
  }
}

// ---------- P0: coalesced-read scatter-write layer-0 weight prep (interleaved hi/lo) ----------
__global__ void prep_w0_scatter(const float* __restrict__ W, f16* __restrict__ dst,
                                const int* __restrict__ pos, const int* __restrict__ meta) {
  int Kpc = meta[1];
  if (Kpc == 0) return;
  int total = 2048 * 3000;  // rows (padded to 2048) x 12000/4
  for (int i = blockIdx.x * 256 + threadIdx.x; i < total; i += gridDim.x * 256) {
    int o = i / 3000;
    int f4 = (i - o * 3000) << 2;
    float w[4] = {0.f, 0.f, 0.f, 0.f};
    if (o < 2000) {
      float4 t = *(const float4*)&W[(size_t)o * 12000 + f4];
      w[0] = t.x; w[1] = t.y; w[2] = t.z; w[3] = t.w;
    }
    int r2 = ((o >> 4) << 5) + (o & 15);  // hi row; +16 = lo row
    size_t rh = (size_t)r2 * Kpc;
    size_t rl = (size_t)(r2 + 16) * Kpc;
#pragma unroll
    for (int e = 0; e < 4; ++e) {
      int p = pos[f4 + e];
      if (p >= 0) {
        f16 h = (f16)w[e];
        float hf = (float)h;
        if (__builtin_fabsf(hf) < 6.103515625e-05f) { h = (f16)0.f; hf = 0.f; }
        f16 l = (f16)((w[e] - hf) * 4096.0f);
        dst[rh + p] = h;
        dst[rl + p] = l;
      }
    }
  }
}

// ---------- zero the [K,Kpc) column pad of the layer-0 W2 ----------
__global__ void zero_tail(f16* __restrict__ dst, const int* __restrict__ meta) {
  int K = meta[0], Kpc = meta[1];
  int i = blockIdx.x * 256 + threadIdx.x;  // 4096*64 threads
  int r2 = i >> 6, j = K + (i & 63);
  if (j < Kpc) dst[(size_t)r2 * Kpc + j] = (f16)0.f;
}

// ---------- weight prep for layers 1..5 (all interleaved W2) ----------
struct PrepArgs {
  const float* W[5];
  f16* dst[5];
  int Nr[5], Kr[5], Kp[5], Npd[5];
  int boff[6];
};

__global__ void prep_w_all(PrepArgs a) {
  int blk = blockIdx.x;
  int k = 0;
#pragma unroll
  for (int j = 0; j < 4; ++j) k += (blk >= a.boff[j + 1]) ? 1 : 0;
  int i = (blk - a.boff[k]) * 256 + threadIdx.x;
  int Kp = a.Kp[k];
  int kp4 = Kp >> 2;
  int total4 = a.Npd[k] * kp4;
  if (i >= total4) return;
  int o = i / kp4, f = (i - o * kp4) << 2;
  float w[4] = {0.f, 0.f, 0.f, 0.f};
  if (o < a.Nr[k] && f < a.Kr[k]) {
    float4 t = *(const float4*)&a.W[k][(size_t)o * a.Kr[k] + f];
    w[0] = t.x; w[1] = t.y; w[2] = t.z; w[3] = t.w;
  }
  f16x4 h4, l4;
#pragma unroll
  for (int e = 0; e < 4; ++e) {
    f16 h = (f16)w[e];
    float hf = (float)h;
    if (__builtin_fabsf(hf) < 6.103515625e-05f) { h = (f16)0.f; hf = 0.f; }
    h4[e] = h;
    l4[e] = (f16)((w[e] - hf) * 4096.0f);
  }
  int r2 = ((o >> 4) << 5) + (o & 15);
  *(f16x4*)&a.dst[k][(size_t)r2 * Kp + f] = h4;
  *(f16x4*)&a.dst[k][(size_t)(r2 + 16) * Kp + f] = l4;
}

// ---------- fused GEMM + LI_k + LIF_{k+1}: BM=256, BN=128 W2-rows, 8 waves ----------
// Rows ordered row = b*32 + t. If Gout != nullptr (last layer): plain f32 C write.
// Else: epilogue runs the exact li_lif fp32 recurrence per (b,col) chain via LDS
// scratch (reuses staging LDS after final barrier) and writes next-layer spikes (f16).
__launch_bounds__(512, 4)
__global__ void gemm_fused(const f16* __restrict__ A, const f16* __restrict__ B2,
                           f16* __restrict__ Spk, float* __restrict__ Gout,
                           const int* __restrict__ kpcp, int KpFixed, int Np) {
  __shared__ f16 smem[256 * 64 + 128 * 64];  // 48 KiB: sA | sB
  f16* sA = smem;
  f16* sB = smem + 256 * 64;
  const int Kp = kpcp ? kpcp[1] : KpFixed;
  const int tid = threadIdx.x;
  const int lane = tid & 63;
  const int wave = tid >> 6;
  const int wr = wave >> 1;
  const int wc = wave & 1;

  const int nx = gridDim.x;
  const int flat = blockIdx.y * nx + blockIdx.x;
  const int cpx = (nx * gridDim.y) >> 3;
  const int id = (flat & 7) * cpx + (flat >> 3);
  const int m0 = (id / nx) * 256;
  const int n0 = (id % nx) * 128;

  f32x4 zero = {0.f, 0.f, 0.f, 0.f};
  f32x4 acc[4][4];
#pragma unroll
  for (int m = 0; m < 4; ++m)
#pragma unroll
    for (int n = 0; n < 4; ++n) acc[m][n] = zero;

  const f16* Abase = A + (size_t)m0 * Kp;
  const f16* Bbase = B2 + (size_t)n0 * Kp;
  const int nkt = Kp >> 6;
  for (int kt = 0; kt < nkt; ++kt) {
    __syncthreads();
    const f16* Ab = Abase + (size_t)kt * 64;
    const f16* Bb = Bbase + (size_t)kt * 64;
#pragma unroll
    for (int j = 0; j < 4; ++j) {
      int q = j * 512 + tid;
      int r = q >> 3, c = ((q & 7) ^ (r & 7)) * 8;
      __builtin_amdgcn_global_load_lds((const AS1 void*)(Ab + (size_t)r * Kp + c),
                                       (AS3 void*)(&sA[q * 8]), 16, 0, 0);
    }
#pragma unroll
    for (int j = 0; j < 2; ++j) {
      int q = j * 512 + tid;
      int r = q >> 3, c = ((q & 7) ^ (r & 7)) * 8;
      __builtin_amdgcn_global_load_lds((const AS1 void*)(Bb + (size_t)r * Kp + c),
                                       (AS3 void*)(&sB[q * 8]), 16, 0, 0);
    }
    __syncthreads();
#pragma unroll
    for (int kk = 0; kk < 2; ++kk) {
      const int lr = lane & 15;
      const int hq = lane >> 4;
      f16x8 af[4], bf[4];
#pragma unroll
      for (int m = 0; m < 4; ++m) {
        int R = wr * 64 + m * 16 + lr;
        int ch = (kk * 4 + hq) ^ (R & 7);
        af[m] = *(const f16x8*)&sA[R * 64 + ch * 8];
      }
#pragma unroll
      for (int n = 0; n < 4; ++n) {
        int R = wc * 64 + n * 16 + lr;
        int ch = (kk * 4 + hq) ^ (R & 7);
        bf[n] = *(const f16x8*)&sB[R * 64 + ch * 8];
      }
#pragma unroll
      for (int m = 0; m < 4; ++m)
#pragma unroll
        for (int n = 0; n < 4; ++n)
          acc[m][n] = __builtin_amdgcn_mfma_f32_16x16x32_f16(af[m], bf[n], acc[m][n], 0, 0, 0);
    }
  }

  const int lr = lane & 15, lq = lane >> 4;
  if (Gout) {  // last layer: plain f32 write (block-uniform branch)
#pragma unroll
    for (int m = 0; m < 4; ++m)
#pragma unroll
      for (int j = 0; j < 2; ++j) {
        int col = (n0 >> 1) + wc * 32 + j * 16 + lr;
#pragma unroll
        for (int i = 0; i < 4; ++i) {
          int row = m0 + wr * 64 + m * 16 + lq * 4 + i;
          Gout[(size_t)row * Np + col] = acc[m][2 * j][i] + EPS_LO * acc[m][2 * j + 1][i];
        }
      }
    return;
  }

  // ---- fused LI+LIF epilogue: per wave, 64 rows (= 2 batches x 32 t) x 32 cols ----
  __syncthreads();                              // all waves done reading LDS tiles
  float* scr = (float*)smem + wave * 1152;      // [64][17] f32, per-wave scratch
  const int baseRow = m0 + wr * 64;             // multiple of 64
#pragma unroll
  for (int h = 0; h < 2; ++h) {
#pragma unroll
    for (int m = 0; m < 4; ++m)
#pragma unroll
      for (int i = 0; i < 4; ++i)
        scr[(m * 16 + lq * 4 + i) * 17 + lr] = acc[m][2 * h][i] + EPS_LO * acc[m][2 * h + 1][i];
    __syncthreads();
    if (lane < 32) {
      int bl = lane >> 4, c = lane & 15;
      float vL = 0.f, iL = 0.f, vF = 0.f, iF = 0.f;
      for (int t = 0; t < 32; ++t) {
        float g = scr[(bl * 32 + t) * 17 + c];
        float ij = iL + g;
        vL = vL + KM * (ij - vL);
        iL = KS * ij;
        float vd = vF + KM * (iF - vF);
        float idec = KS * iF;
        float z = (vd > 1.0f) ? 1.f : 0.f;
        vF = (1.f - z) * vd;
        iF = idec + vL;
        scr[(bl * 32 + t) * 17 + c] = z;
      }
    }
    __syncthreads();
    {
      int row = lane;
      f16x8 v0, v1;
#pragma unroll
      for (int cc = 0; cc < 8; ++cc) {
        v0[cc] = (f16)scr[row * 17 + cc];
        v1[cc] = (f16)scr[row * 17 + 8 + cc];
      }
      size_t go = (size_t)(baseRow + row) * Np + (n0 >> 1) + wc * 32 + h * 16;
      *(f16x8*)&Spk[go] = v0;
      *(f16x8*)&Spk[go + 8] = v1;
    }
    __syncthreads();
  }
}

// ---------- LI5 scan + max over t + log_softmax (rows = b*32+t) ----------
__global__ void final_k(const float* __restrict__ G, float* __restrict__ out) {
  int b = blockIdx.x;
  int n = threadIdx.x;
  float vL = 0.f, iL = 0.f, mx = -3.4e38f;
  for (int t = 0; t < 32; ++t) {
    float g = G[(size_t)(b * 32 + t) * 128 + n];
    float ij = iL + g;
    vL = vL + KM * (ij - vL);
    iL = KS * ij;
    mx = fmaxf(mx, vL);
  }
  float v = (n < 10) ? mx : -3.4e38f;
  float M = v;
#pragma unroll
  for (int s = 1; s < 16; s <<= 1) M = fmaxf(M, __shfl_xor(M, s));
  float e = (n < 10) ? expf(v - M) : 0.f;
  float sum = e;
#pragma unroll
  for (int s = 1; s < 16; s <<= 1) sum += __shfl_xor(sum, s);
  if (n < 10) out[b * 10 + n] = v - M - logf(sum);
}

extern "C" void kernel_launch(void* const* d_in, const int* in_sizes, int n_in,
                              void* d_out, int out_size, void* d_ws, size_t ws_size,
                              hipStream_t stream) {
  const float* img = (const float*)d_in[0];
  static const int Nr[6]  = {2000, 1500, 1000, 500, 100, 10};
  static const int Kr[6]  = {12000, 2000, 1500, 1000, 500, 100};
  static const int Npd[6] = {2048, 1536, 1024, 512, 128, 128};
  static const int Kpd[6] = {12032, 2048, 1536, 1024, 512, 128};

  char* p = (char*)d_ws;
  f16* wa[6];  // interleaved W2 [2*Npd][Kp] (layer 0: compacted K)
  wa[0] = (f16*)p; p += (size_t)4096 * 12032 * 2;  // max compacted size
  for (int k = 1; k < 6; ++k) {
    wa[k] = (f16*)p; p += (size_t)2 * Npd[k] * Kpd[k] * 2;
  }
  f16* Sbig = (f16*)p; p += (size_t)4096 * 12032 * 2;  // compacted L0 A
  f16* T0 = (f16*)p;   p += (size_t)4096 * 2048 * 2;   // spike ping
  f16* T1 = (f16*)p;   p += (size_t)4096 * 2048 * 2;   // spike pong
  float* G = (float*)p; p += (size_t)4096 * 128 * 4;   // L5 output only
  uint* Z = (uint*)p; p += (size_t)128 * 12032 * 4;    // spike bitmasks
  uint* flags = (uint*)p; p += 376 * 4;
  int* colidx = (int*)p; p += 12032 * 4;
  int* pos = (int*)p; p += 12032 * 4;
  int* meta = (int*)p; p += 2 * 4;

  // --- layer-0 column compaction chain ---
  hipMemsetAsync(flags, 0, 376 * 4, stream);
  enc_flags<<<(128 * 3000 + 255) / 256, 256, 0, stream>>>(img, Z, flags);
  scan_cols<<<1, 512, 0, stream>>>(flags, colidx, pos, meta);
  spike_gather<<<1024, 256, 0, stream>>>(Z, Sbig, colidx, meta);
  prep_w0_scatter<<<8192, 256, 0, stream>>>((const float*)d_in[1], wa[0], pos, meta);
  zero_tail<<<(4096 * 64) / 256, 256, 0, stream>>>(wa[0], meta);

  // --- layers 1..5 weight prep ---
  PrepArgs pa;
  int nb = 0;
  for (int k = 1; k < 6; ++k) {
    int kk = k - 1;
    pa.W[kk] = (const float*)d_in[k + 1];
    pa.dst[kk] = wa[k];
    pa.Nr[kk] = Nr[k]; pa.Kr[kk] = Kr[k]; pa.Kp[kk] = Kpd[k]; pa.Npd[kk] = Npd[k];
    pa.boff[kk] = nb;
    nb += ((Npd[k] * Kpd[k]) >> 2) / 256;
  }
  pa.boff[5] = nb;
  prep_w_all<<<nb, 256, 0, stream>>>(pa);

  // --- fused layer pipeline (spikes ping-pong T0/T1) ---
  const f16* Ain = Sbig;
  f16* T[2] = {T0, T1};
  for (int k = 0; k < 6; ++k) {
    f16* Sout = (k < 5) ? T[k & 1] : nullptr;
    float* Gout = (k == 5) ? G : nullptr;
    gemm_fused<<<dim3(2 * Npd[k] / 128, 16), dim3(512), 0, stream>>>(
        Ain, wa[k], Sout, Gout, (k == 0) ? meta : nullptr, Kpd[k], Npd[k]);
    Ain = T[k & 1];
  }
  final_k<<<128, 64, 0, stream>>>(G, (float*)d_out);
}

// Round 10
// 285.670 us; speedup vs baseline: 1.1325x; 1.0781x over previous
//
#include <hip/hip_runtime.h>

typedef _Float16 f16;
typedef _Float16 f16x2 __attribute__((ext_vector_type(2)));
typedef _Float16 f16x4 __attribute__((ext_vector_type(4)));
typedef _Float16 f16x8 __attribute__((ext_vector_type(8)));
typedef float f32x4 __attribute__((ext_vector_type(4)));
typedef unsigned int uint;

#define KM 0.1f   // DT * TAU_MEM_INV
#define KS 0.8f   // 1 - DT * TAU_SYN_INV
#define AS1 __attribute__((address_space(1)))
#define AS3 __attribute__((address_space(3)))
#define EPS_LO 2.44140625e-4f  // 2^-12

// ---------- E1: enc+LIF0 sim (float4) -> spike bitmask Z[b][f] + column flags ----------
__global__ void enc_flags(const float* __restrict__ img, uint* __restrict__ Z,
                          uint* __restrict__ flags) {
  int idx = blockIdx.x * 256 + threadIdx.x;
  if (idx >= 128 * 3000) return;
  int b = idx / 3000, f = (idx - b * 3000) << 2;
  float4 t4 = *(const float4*)&img[b * 12000 + f];
  float x[4] = {t4.x, t4.y, t4.z, t4.w};
  float ve[4] = {0.f, 0.f, 0.f, 0.f}, vl[4] = {0.f, 0.f, 0.f, 0.f}, il[4] = {0.f, 0.f, 0.f, 0.f};
  uint m[4] = {0u, 0u, 0u, 0u};
  for (int t = 0; t < 32; ++t) {
#pragma unroll
    for (int e = 0; e < 4; ++e) {
      ve[e] = ve[e] + KM * (x[e] - ve[e]);
      float z0 = (ve[e] > 1.0f) ? 1.f : 0.f;
      ve[e] -= z0 * ve[e];
      float vd = vl[e] + KM * (il[e] - vl[e]);
      float id = KS * il[e];
      float z1 = (vd > 1.0f) ? 1.f : 0.f;
      m[e] |= (vd > 1.0f) ? (1u << t) : 0u;
      vl[e] = (1.f - z1) * vd;
      il[e] = id + z0;
    }
  }
  *(uint4*)&Z[b * 12032 + f] = make_uint4(m[0], m[1], m[2], m[3]);
  uint mask = 0u;
#pragma unroll
  for (int e = 0; e < 4; ++e) mask |= (m[e] ? 1u : 0u) << ((f & 31) + e);
  int lane = threadIdx.x & 63;
#pragma unroll
  for (int s = 1; s < 8; s <<= 1) mask |= (uint)__shfl_xor((int)mask, s);
  if ((lane & 7) == 0 && mask) atomicOr(&flags[f >> 5], mask);
}

// ---------- E2: popcount scan -> sorted colidx, meta={K', Kpc} ----------
__global__ void scan_cols(const uint* __restrict__ flags, int* __restrict__ colidx,
                          int* __restrict__ meta) {
  __shared__ int cnt[512];
  int t = threadIdx.x;
  uint w = (t < 376) ? flags[t] : 0u;
  cnt[t] = __popc(w);
  __syncthreads();
  for (int off = 1; off < 512; off <<= 1) {
    int v = cnt[t];
    int u = (t >= off) ? cnt[t - off] : 0;
    __syncthreads();
    cnt[t] = v + u;
    __syncthreads();
  }
  int base = cnt[t] - __popc(w);  // exclusive prefix
  uint ww = w;
  int r = 0;
  while (ww) {
    int p = __ffs(ww) - 1;
    colidx[base + r] = t * 32 + p;
    ww &= ww - 1;
    ++r;
  }
  if (t == 511) {
    int K = cnt[511];
    meta[0] = K;
    meta[1] = (K + 63) & ~63;
  }
}

// ---------- E3: compacted A'[4096][Kpc] from Z bitmasks; row = b*32 + t ----------
__global__ void spike_gather(const uint* __restrict__ Z, f16* __restrict__ A,
                             const int* __restrict__ colidx, const int* __restrict__ meta) {
  int K = meta[0], Kpc = meta[1];
  if (Kpc == 0) return;
  int jp = Kpc >> 1;
  int total = 128 * jp;
  for (int i = blockIdx.x * 256 + threadIdx.x; i < total; i += gridDim.x * 256) {
    int b = i / jp, j = (i - b * jp) << 1;
    uint m0 = (j < K) ? Z[b * 12032 + colidx[j]] : 0u;
    uint m1 = (j + 1 < K) ? Z[b * 12032 + colidx[j + 1]] : 0u;
    size_t rowbase = (size_t)b * 32 * Kpc + j;
    for (int t = 0; t < 32; ++t) {
      f16x2 s;
      s[0] = (f16)(float)((m0 >> t) & 1u);
      s[1] = (f16)(float)((m1 >> t) & 1u);
      *(f16x2*)&A[rowbase + (size_t)t * Kpc] = s;
    }
  }
}

// ---------- P0: gather-read, coalesced-write layer-0 weight prep (interleaved hi/lo) ----------
// Reads W[o][colidx[j]] (sorted -> line-local), writes f16x8 hi row + lo row. Pad = 0.
__global__ void prep_w0_gather(const float* __restrict__ W, f16* __restrict__ dst,
                               const int* __restrict__ colidx, const int* __restrict__ meta) {
  int K = meta[0], Kpc = meta[1];
  if (Kpc == 0) return;
  int kq = Kpc >> 3;
  int total = 2048 * kq;
  for (int i = blockIdx.x * 256 + threadIdx.x; i < total; i += gridDim.x * 256) {
    int o = i / kq, j8 = (i - o * kq) << 3;
    f16x8 h8, l8;
#pragma unroll
    for (int e = 0; e < 8; ++e) {
      int j = j8 + e;
      float w = 0.f;
      if (j < K && o < 2000) w = W[(size_t)o * 12000 + colidx[j]];
      f16 h = (f16)w;
      float hf = (float)h;
      if (__builtin_fabsf(hf) < 6.103515625e-05f) { h = (f16)0.f; hf = 0.f; }
      h8[e] = h;
      l8[e] = (f16)((w - hf) * 4096.0f);
    }
    int r2 = ((o >> 4) << 5) + (o & 15);  // hi row; +16 = lo row
    *(f16x8*)&dst[(size_t)r2 * Kpc + j8] = h8;
    *(f16x8*)&dst[(size_t)(r2 + 16) * Kpc + j8] = l8;
  }
}

// ---------- weight prep for layers 1..5 (all interleaved W2) ----------
struct PrepArgs {
  const float* W[5];
  f16* dst[5];
  int Nr[5], Kr[5], Kp[5], Npd[5];
  int boff[6];
};

__global__ void prep_w_all(PrepArgs a) {
  int blk = blockIdx.x;
  int k = 0;
#pragma unroll
  for (int j = 0; j < 4; ++j) k += (blk >= a.boff[j + 1]) ? 1 : 0;
  int i = (blk - a.boff[k]) * 256 + threadIdx.x;
  int Kp = a.Kp[k];
  int kp4 = Kp >> 2;
  int total4 = a.Npd[k] * kp4;
  if (i >= total4) return;
  int o = i / kp4, f = (i - o * kp4) << 2;
  float w[4] = {0.f, 0.f, 0.f, 0.f};
  if (o < a.Nr[k] && f < a.Kr[k]) {
    float4 t = *(const float4*)&a.W[k][(size_t)o * a.Kr[k] + f];
    w[0] = t.x; w[1] = t.y; w[2] = t.z; w[3] = t.w;
  }
  f16x4 h4, l4;
#pragma unroll
  for (int e = 0; e < 4; ++e) {
    f16 h = (f16)w[e];
    float hf = (float)h;
    if (__builtin_fabsf(hf) < 6.103515625e-05f) { h = (f16)0.f; hf = 0.f; }
    h4[e] = h;
    l4[e] = (f16)((w[e] - hf) * 4096.0f);
  }
  int r2 = ((o >> 4) << 5) + (o & 15);
  *(f16x4*)&a.dst[k][(size_t)r2 * Kp + f] = h4;
  *(f16x4*)&a.dst[k][(size_t)(r2 + 16) * Kp + f] = l4;
}

// ---------- fused GEMM + LI_k + LIF_{k+1}, templated on wave-rows ----------
// WM=4: BM=256, 512 thr (layers 0,1). WM=2: BM=128, 256 thr (layers 2..5, better TLP).
// Rows ordered row = b*32 + t. Gout != nullptr (last layer): plain f32 C write.
// Else: epilogue runs exact li_lif fp32 recurrence via per-wave LDS scratch and
// writes next-layer spikes (f16, coalesced).
template <int WM>
__global__ __launch_bounds__(WM * 128, 4)
void gemm_fused(const f16* __restrict__ A, const f16* __restrict__ B2,
                f16* __restrict__ Spk, float* __restrict__ Gout,
                const int* __restrict__ kpcp, int KpFixed, int Np) {
  constexpr int BM = WM * 64;
  constexpr int NT = WM * 128;
  constexpr int BI = 1024 / NT;
  __shared__ f16 smem[BM * 64 + 128 * 64];
  f16* sA = smem;
  f16* sB = smem + BM * 64;
  const int Kp = kpcp ? kpcp[1] : KpFixed;
  const int tid = threadIdx.x;
  const int lane = tid & 63;
  const int wave = tid >> 6;
  const int wr = wave >> 1;
  const int wc = wave & 1;

  const int nx = gridDim.x;
  const int flat = blockIdx.y * nx + blockIdx.x;
  const int cpx = (nx * gridDim.y) >> 3;
  const int id = (flat & 7) * cpx + (flat >> 3);
  const int m0 = (id / nx) * BM;
  const int n0 = (id % nx) * 128;

  f32x4 zero = {0.f, 0.f, 0.f, 0.f};
  f32x4 acc[4][4];
#pragma unroll
  for (int m = 0; m < 4; ++m)
#pragma unroll
    for (int n = 0; n < 4; ++n) acc[m][n] = zero;

  const f16* Abase = A + (size_t)m0 * Kp;
  const f16* Bbase = B2 + (size_t)n0 * Kp;
  const int nkt = Kp >> 6;
  for (int kt = 0; kt < nkt; ++kt) {
    __syncthreads();
    const f16* Ab = Abase + (size_t)kt * 64;
    const f16* Bb = Bbase + (size_t)kt * 64;
#pragma unroll
    for (int j = 0; j < 4; ++j) {  // A: BM*8 chunks = 4*NT
      int q = j * NT + tid;
      int r = q >> 3, c = ((q & 7) ^ (r & 7)) * 8;
      __builtin_amdgcn_global_load_lds((const AS1 void*)(Ab + (size_t)r * Kp + c),
                                       (AS3 void*)(&sA[q * 8]), 16, 0, 0);
    }
#pragma unroll
    for (int j = 0; j < BI; ++j) {  // B: 1024 chunks
      int q = j * NT + tid;
      int r = q >> 3, c = ((q & 7) ^ (r & 7)) * 8;
      __builtin_amdgcn_global_load_lds((const AS1 void*)(Bb + (size_t)r * Kp + c),
                                       (AS3 void*)(&sB[q * 8]), 16, 0, 0);
    }
    __syncthreads();
#pragma unroll
    for (int kk = 0; kk < 2; ++kk) {
      const int lr = lane & 15;
      const int hq = lane >> 4;
      f16x8 af[4], bf[4];
#pragma unroll
      for (int m = 0; m < 4; ++m) {
        int R = wr * 64 + m * 16 + lr;
        int ch = (kk * 4 + hq) ^ (R & 7);
        af[m] = *(const f16x8*)&sA[R * 64 + ch * 8];
      }
#pragma unroll
      for (int n = 0; n < 4; ++n) {
        int R = wc * 64 + n * 16 + lr;
        int ch = (kk * 4 + hq) ^ (R & 7);
        bf[n] = *(const f16x8*)&sB[R * 64 + ch * 8];
      }
#pragma unroll
      for (int m = 0; m < 4; ++m)
#pragma unroll
        for (int n = 0; n < 4; ++n)
          acc[m][n] = __builtin_amdgcn_mfma_f32_16x16x32_f16(af[m], bf[n], acc[m][n], 0, 0, 0);
    }
  }

  const int lr = lane & 15, lq = lane >> 4;
  if (Gout) {  // last layer: plain f32 write (block-uniform branch)
#pragma unroll
    for (int m = 0; m < 4; ++m)
#pragma unroll
      for (int j = 0; j < 2; ++j) {
        int col = (n0 >> 1) + wc * 32 + j * 16 + lr;
#pragma unroll
        for (int i = 0; i < 4; ++i) {
          int row = m0 + wr * 64 + m * 16 + lq * 4 + i;
          Gout[(size_t)row * Np + col] = acc[m][2 * j][i] + EPS_LO * acc[m][2 * j + 1][i];
        }
      }
    return;
  }

  // ---- fused LI+LIF epilogue: per wave, 64 rows (= 2 batches x 32 t) x 32 cols ----
  __syncthreads();
  float* scr = (float*)smem + wave * 1152;  // [64][17] f32 per-wave scratch
  const int baseRow = m0 + wr * 64;
#pragma unroll
  for (int h = 0; h < 2; ++h) {
#pragma unroll
    for (int m = 0; m < 4; ++m)
#pragma unroll
      for (int i = 0; i < 4; ++i)
        scr[(m * 16 + lq * 4 + i) * 17 + lr] = acc[m][2 * h][i] + EPS_LO * acc[m][2 * h + 1][i];
    __syncthreads();
    if (lane < 32) {
      int bl = lane >> 4, c = lane & 15;
      float vL = 0.f, iL = 0.f, vF = 0.f, iF = 0.f;
      for (int t = 0; t < 32; ++t) {
        float g = scr[(bl * 32 + t) * 17 + c];
        float ij = iL + g;
        vL = vL + KM * (ij - vL);
        iL = KS * ij;
        float vd = vF + KM * (iF - vF);
        float idec = KS * iF;
        float z = (vd > 1.0f) ? 1.f : 0.f;
        vF = (1.f - z) * vd;
        iF = idec + vL;
        scr[(bl * 32 + t) * 17 + c] = z;
      }
    }
    __syncthreads();
    {
      int row = lane;
      f16x8 v0, v1;
#pragma unroll
      for (int cc = 0; cc < 8; ++cc) {
        v0[cc] = (f16)scr[row * 17 + cc];
        v1[cc] = (f16)scr[row * 17 + 8 + cc];
      }
      size_t go = (size_t)(baseRow + row) * Np + (n0 >> 1) + wc * 32 + h * 16;
      *(f16x8*)&Spk[go] = v0;
      *(f16x8*)&Spk[go + 8] = v1;
    }
    __syncthreads();
  }
}

// ---------- LI5 scan + max over t + log_softmax (rows = b*32+t) ----------
__global__ void final_k(const float* __restrict__ G, float* __restrict__ out) {
  int b = blockIdx.x;
  int n = threadIdx.x;
  float vL = 0.f, iL = 0.f, mx = -3.4e38f;
  for (int t = 0; t < 32; ++t) {
    float g = G[(size_t)(b * 32 + t) * 128 + n];
    float ij = iL + g;
    vL = vL + KM * (ij - vL);
    iL = KS * ij;
    mx = fmaxf(mx, vL);
  }
  float v = (n < 10) ? mx : -3.4e38f;
  float M = v;
#pragma unroll
  for (int s = 1; s < 16; s <<= 1) M = fmaxf(M, __shfl_xor(M, s));
  float e = (n < 10) ? expf(v - M) : 0.f;
  float sum = e;
#pragma unroll
  for (int s = 1; s < 16; s <<= 1) sum += __shfl_xor(sum, s);
  if (n < 10) out[b * 10 + n] = v - M - logf(sum);
}

extern "C" void kernel_launch(void* const* d_in, const int* in_sizes, int n_in,
                              void* d_out, int out_size, void* d_ws, size_t ws_size,
                              hipStream_t stream) {
  const float* img = (const float*)d_in[0];
  static const int Nr[6]  = {2000, 1500, 1000, 500, 100, 10};
  static const int Kr[6]  = {12000, 2000, 1500, 1000, 500, 100};
  static const int Npd[6] = {2048, 1536, 1024, 512, 128, 128};
  static const int Kpd[6] = {12032, 2048, 1536, 1024, 512, 128};

  char* p = (char*)d_ws;
  f16* wa[6];  // interleaved W2 [2*Npd][Kp] (layer 0: compacted K)
  wa[0] = (f16*)p; p += (size_t)4096 * 12032 * 2;  // max compacted size
  for (int k = 1; k < 6; ++k) {
    wa[k] = (f16*)p; p += (size_t)2 * Npd[k] * Kpd[k] * 2;
  }
  f16* Sbig = (f16*)p; p += (size_t)4096 * 12032 * 2;  // compacted L0 A
  f16* T0 = (f16*)p;   p += (size_t)4096 * 2048 * 2;   // spike ping
  f16* T1 = (f16*)p;   p += (size_t)4096 * 2048 * 2;   // spike pong
  float* G = (float*)p; p += (size_t)4096 * 128 * 4;   // L5 output only
  uint* Z = (uint*)p; p += (size_t)128 * 12032 * 4;    // spike bitmasks
  uint* flags = (uint*)p; p += 376 * 4;
  int* colidx = (int*)p; p += 12032 * 4;
  int* meta = (int*)p; p += 2 * 4;

  // --- layer-0 column compaction chain ---
  hipMemsetAsync(flags, 0, 376 * 4, stream);
  enc_flags<<<(128 * 3000 + 255) / 256, 256, 0, stream>>>(img, Z, flags);
  scan_cols<<<1, 512, 0, stream>>>(flags, colidx, meta);
  spike_gather<<<1024, 256, 0, stream>>>(Z, Sbig, colidx, meta);
  prep_w0_gather<<<4096, 256, 0, stream>>>((const float*)d_in[1], wa[0], colidx, meta);

  // --- layers 1..5 weight prep ---
  PrepArgs pa;
  int nb = 0;
  for (int k = 1; k < 6; ++k) {
    int kk = k - 1;
    pa.W[kk] = (const float*)d_in[k + 1];
    pa.dst[kk] = wa[k];
    pa.Nr[kk] = Nr[k]; pa.Kr[kk] = Kr[k]; pa.Kp[kk] = Kpd[k]; pa.Npd[kk] = Npd[k];
    pa.boff[kk] = nb;
    nb += ((Npd[k] * Kpd[k]) >> 2) / 256;
  }
  pa.boff[5] = nb;
  prep_w_all<<<nb, 256, 0, stream>>>(pa);

  // --- fused layer pipeline (spikes ping-pong T0/T1) ---
  const f16* Ain = Sbig;
  f16* T[2] = {T0, T1};
  for (int k = 0; k < 6; ++k) {
    f16* Sout = (k < 5) ? T[k & 1] : nullptr;
    float* Gout = (k == 5) ? G : nullptr;
    const int* kp = (k == 0) ? meta : nullptr;
    if (k < 2) {
      gemm_fused<4><<<dim3(2 * Npd[k] / 128, 16), dim3(512), 0, stream>>>(
          Ain, wa[k], Sout, Gout, kp, Kpd[k], Npd[k]);
    } else {
      gemm_fused<2><<<dim3(2 * Npd[k] / 128, 32), dim3(256), 0, stream>>>(
          Ain, wa[k], Sout, Gout, kp, Kpd[k], Npd[k]);
    }
    Ain = T[k & 1];
  }
  final_k<<<128, 64, 0, stream>>>(G, (float*)d_out);
}